// Round 6
// baseline (439.399 us; speedup 1.0000x reference)
//
#include <hip/hip_runtime.h>

#define BB 32
#define CC 512
#define HWN 1024
#define DD 64
#define OO 640  // 2*DD + CC

typedef short bf16x8 __attribute__((ext_vector_type(8)));
typedef float f32x4 __attribute__((ext_vector_type(4)));
typedef __attribute__((address_space(1))) const void gvoid;
typedef __attribute__((address_space(3))) void svoid;

__device__ __forceinline__ void gload_lds16(const void* g, void* l) {
    __builtin_amdgcn_global_load_lds((gvoid*)g, (svoid*)l, 16, 0, 0);
}

__device__ __forceinline__ unsigned short f2bf(float f) {
    unsigned int u = __float_as_uint(f);
    unsigned int r = u + 0x7FFFu + ((u >> 16) & 1u);  // RNE
    return (unsigned short)(r >> 16);
}
__device__ __forceinline__ float bf2f(unsigned short h) {
    return __uint_as_float(((unsigned int)h) << 16);
}

// ---------------- f32 -> bf16 convert (weights) ----------------
__global__ __launch_bounds__(256) void cvt_bf16_kernel(const float* __restrict__ in,
                                                       unsigned short* __restrict__ out, int n) {
    int i = blockIdx.x * 256 + threadIdx.x;
    if (i < n) out[i] = f2bf(in[i]);
}

__global__ __launch_bounds__(256) void zero_kernel(float* __restrict__ p, int n) {
    int i = blockIdx.x * 256 + threadIdx.x;
    if (i < n) p[i] = 0.f;
}

__global__ __launch_bounds__(256) void finalize_bn2_kernel(const float* __restrict__ bnsum,
                                                           float* __restrict__ mean,
                                                           float* __restrict__ rstd) {
    int c = blockIdx.x * 256 + threadIdx.x;
    if (c < CC) {
        const float invN = 1.f / (float)(BB * HWN);
        float m = bnsum[c] * invN;
        float var = bnsum[CC + c] * invN - m * m;
        mean[c] = m;
        rstd[c] = rsqrtf(var + 1e-5f);
    }
}

// ---------------- BN stats: one block per channel; input f32 ----------------
__global__ __launch_bounds__(256) void bn_stats_kernel(const float* __restrict__ x,
                                                       float* __restrict__ mean,
                                                       float* __restrict__ rstd) {
    int c = blockIdx.x;
    int t = threadIdx.x;
    float s = 0.f, s2 = 0.f;
    for (int b = 0; b < BB; ++b) {
        const float4* p = (const float4*)(x + ((size_t)b * CC + c) * HWN);
        float4 v = p[t];
        s += v.x + v.y + v.z + v.w;
        s2 += v.x * v.x + v.y * v.y + v.z * v.z + v.w * v.w;
    }
    for (int off = 32; off > 0; off >>= 1) {
        s  += __shfl_down(s,  off, 64);
        s2 += __shfl_down(s2, off, 64);
    }
    __shared__ float sh[4], sh2[4];
    int wave = t >> 6;
    if ((t & 63) == 0) { sh[wave] = s; sh2[wave] = s2; }
    __syncthreads();
    if (t == 0) {
        float ts = 0.f, ts2 = 0.f;
        for (int w = 0; w < 4; ++w) { ts += sh[w]; ts2 += sh2[w]; }
        const float invN = 1.f / (float)(BB * HWN);
        float m = ts * invN;
        float var = ts2 * invN - m * m;
        mean[c] = m;
        rstd[c] = rsqrtf(var + 1e-5f);
    }
}

// ------- BN apply + transpose: x[b][c][s] -> outT[b][s][c] bf16 (+relu) -------
template <bool RELU, bool INBF16>
__global__ __launch_bounds__(256) void bn_apply_t_kernel(const void* __restrict__ xv,
                                                         const float* __restrict__ mean,
                                                         const float* __restrict__ rstd,
                                                         const float* __restrict__ g,
                                                         const float* __restrict__ bta,
                                                         unsigned short* __restrict__ outT) {
    __shared__ float tile[64][65];
    int b  = blockIdx.z;
    int c0 = blockIdx.y * 64;
    int s0 = blockIdx.x * 64;
    int t = threadIdx.x;
    int sl = t & 63, grp = t >> 6;
#pragma unroll
    for (int i = 0; i < 16; ++i) {
        int cr = i * 4 + grp;
        int c = c0 + cr;
        float r  = rstd[c] * g[c];
        float sh = bta[c] - mean[c] * r;
        float xval;
        if (INBF16) {
            const unsigned short* xb = (const unsigned short*)xv;
            xval = bf2f(xb[((size_t)b * CC + c0 + cr) * HWN + s0 + sl]);
        } else {
            const float* xb = (const float*)xv;
            xval = xb[((size_t)b * CC + c0 + cr) * HWN + s0 + sl];
        }
        float v = fmaf(xval, r, sh);
        if (RELU) v = fmaxf(v, 0.f);
        tile[cr][sl] = v;
    }
    __syncthreads();
    unsigned short* ob = outT + ((size_t)b * HWN + s0) * CC + c0;
#pragma unroll
    for (int i = 0; i < 16; ++i) {
        int srow = i * 4 + grp;
        ob[(size_t)srow * CC + sl] = f2bf(tile[sl][srow]);
    }
}

// ---------------- row softmax on bf16 [nrows][1024], in place ----------------
__global__ __launch_bounds__(256) void softmax_row_kernel(unsigned short* __restrict__ p) {
    int row = blockIdx.x * 4 + (threadIdx.x >> 6);
    int L = threadIdx.x & 63;
    unsigned short* pr = p + (size_t)row * HWN;
    uint4 d0 = *(const uint4*)(pr + L * 16);
    uint4 d1 = *(const uint4*)(pr + L * 16 + 8);
    float v[16];
    unsigned int w[8] = {d0.x, d0.y, d0.z, d0.w, d1.x, d1.y, d1.z, d1.w};
#pragma unroll
    for (int i = 0; i < 8; ++i) {
        v[2 * i]     = bf2f((unsigned short)(w[i] & 0xffffu));
        v[2 * i + 1] = bf2f((unsigned short)(w[i] >> 16));
    }
    float m = -1e30f;
#pragma unroll
    for (int i = 0; i < 16; ++i) m = fmaxf(m, v[i]);
    for (int off = 32; off > 0; off >>= 1) m = fmaxf(m, __shfl_xor(m, off, 64));
    float s = 0.f;
#pragma unroll
    for (int i = 0; i < 16; ++i) { v[i] = __expf(v[i] - m); s += v[i]; }
    for (int off = 32; off > 0; off >>= 1) s += __shfl_xor(s, off, 64);
    float inv = 1.f / s;
    unsigned int o[8];
#pragma unroll
    for (int i = 0; i < 8; ++i) {
        unsigned int lo = f2bf(v[2 * i] * inv);
        unsigned int hi = f2bf(v[2 * i + 1] * inv);
        o[i] = lo | (hi << 16);
    }
    *(uint4*)(pr + L * 16)     = make_uint4(o[0], o[1], o[2], o[3]);
    *(uint4*)(pr + L * 16 + 8) = make_uint4(o[4], o[5], o[6], o[7]);
}

// ---------------- MFMA bf16 GEMM: C[b] = scale*(A @ Bt^T) (+bias)(+relu)(+resid) ----
// A:  M x K bf16 row-major (k-contiguous), Bt: N x K bf16 row-major (k-contiguous).
// C: M x N (fp32 or bf16), resid fp32 or bf16, same geometry as C.
// Tile 128x128, BK=32, 256 thr = 4 waves (2x2 of 64x64), dbuf LDS, 1 barrier/iter.
// STAGE 0: global_load_lds (LDS-DMA). STAGE 1: buffer_load->VGPR->ds_write.
// XOR-swizzled chunk placement -> conflict-free ds_read_b128.
// BNSTAT: accumulate per-row sum/sum^2 of final C values into bnsum[0..M),bnsum[512+...).
template <bool OUTBF16, int BIASMODE /*0,1 row,2 col*/, bool RELU, int RESMODE /*0,1=f32,2=bf16*/,
          int STAGE, bool BNSTAT>
__global__ __launch_bounds__(256) void mfma_gemm(const unsigned short* __restrict__ A,
                                                 const unsigned short* __restrict__ Bt,
                                                 const float* __restrict__ bias,
                                                 const void* __restrict__ resid,
                                                 void* __restrict__ C,
                                                 float* __restrict__ bnsum,
                                                 int K, int lda, int ldb, int ldc,
                                                 long strideA, long strideB, long strideC,
                                                 float scale) {
    __shared__ __align__(16) unsigned short As[2][128 * 32];
    __shared__ __align__(16) unsigned short Bs[2][128 * 32];
    int b  = blockIdx.z;
    int m0 = blockIdx.y * 128;
    int n0 = blockIdx.x * 128;
    const unsigned short* Ab = A  + (size_t)b * strideA;
    const unsigned short* Bb = Bt + (size_t)b * strideB;
    int t = threadIdx.x;
    int wv = t >> 6, L = t & 63;
    int wm = (wv >> 1) * 64, wn = (wv & 1) * 64;
    int lr = L & 15, lq = L >> 4;
    int srow = t >> 2;                       // staged row 0..63 (per half)
    int gchunk = (t & 3) ^ ((t >> 3) & 3);   // global 16B chunk, swizzle-matched
    int skof = gchunk * 8;                   // bf16 elem offset in k
    int swz = (lr >> 1) & 3;                 // read-side swizzle

    int aoff[4], boff[4];
#pragma unroll
    for (int i = 0; i < 4; ++i) {
        aoff[i] = (wm + i * 16 + lr) * 32 + ((lq ^ swz) * 8);
        boff[i] = (wn + i * 16 + lr) * 32 + ((lq ^ swz) * 8);
    }

    const unsigned short* gA0 = Ab + (size_t)(m0 + srow) * lda + skof;
    const unsigned short* gA1 = Ab + (size_t)(m0 + 64 + srow) * lda + skof;
    const unsigned short* gB0 = Bb + (size_t)(n0 + srow) * ldb + skof;
    const unsigned short* gB1 = Bb + (size_t)(n0 + 64 + srow) * ldb + skof;

    f32x4 acc[4][4] = {};
    int nIter = K >> 5;
    int p = 0;

    if (STAGE == 0) {
        gload_lds16(gA0, &As[0][t * 8]);
        gload_lds16(gA1, &As[0][64 * 32 + t * 8]);
        gload_lds16(gB0, &Bs[0][t * 8]);
        gload_lds16(gB1, &Bs[0][64 * 32 + t * 8]);
        for (int i = 0; i < nIter; ++i) {
            __syncthreads();
            if (i + 1 < nIter) {
                int ko = (i + 1) << 5;
                gload_lds16(gA0 + ko, &As[p ^ 1][t * 8]);
                gload_lds16(gA1 + ko, &As[p ^ 1][64 * 32 + t * 8]);
                gload_lds16(gB0 + ko, &Bs[p ^ 1][t * 8]);
                gload_lds16(gB1 + ko, &Bs[p ^ 1][64 * 32 + t * 8]);
            }
            bf16x8 af[4], bfr[4];
#pragma unroll
            for (int j = 0; j < 4; ++j) af[j]  = *(const bf16x8*)&As[p][aoff[j]];
#pragma unroll
            for (int j = 0; j < 4; ++j) bfr[j] = *(const bf16x8*)&Bs[p][boff[j]];
#pragma unroll
            for (int ii = 0; ii < 4; ++ii)
#pragma unroll
                for (int jj = 0; jj < 4; ++jj)
                    acc[ii][jj] = __builtin_amdgcn_mfma_f32_16x16x32_bf16(af[ii], bfr[jj], acc[ii][jj], 0, 0, 0);
            p ^= 1;
        }
    } else {
        // VGPR staging: classic buffer_load -> ds_write, 1 barrier/iter, dbuf.
        uint4 ra0 = *(const uint4*)gA0;
        uint4 ra1 = *(const uint4*)gA1;
        uint4 rb0 = *(const uint4*)gB0;
        uint4 rb1 = *(const uint4*)gB1;
        for (int i = 0; i < nIter; ++i) {
            *(uint4*)&As[p][t * 8]           = ra0;
            *(uint4*)&As[p][64 * 32 + t * 8] = ra1;
            *(uint4*)&Bs[p][t * 8]           = rb0;
            *(uint4*)&Bs[p][64 * 32 + t * 8] = rb1;
            __syncthreads();
            if (i + 1 < nIter) {
                int ko = (i + 1) << 5;
                ra0 = *(const uint4*)(gA0 + ko);
                ra1 = *(const uint4*)(gA1 + ko);
                rb0 = *(const uint4*)(gB0 + ko);
                rb1 = *(const uint4*)(gB1 + ko);
            }
            bf16x8 af[4], bfr[4];
#pragma unroll
            for (int j = 0; j < 4; ++j) af[j]  = *(const bf16x8*)&As[p][aoff[j]];
#pragma unroll
            for (int j = 0; j < 4; ++j) bfr[j] = *(const bf16x8*)&Bs[p][boff[j]];
#pragma unroll
            for (int ii = 0; ii < 4; ++ii)
#pragma unroll
                for (int jj = 0; jj < 4; ++jj)
                    acc[ii][jj] = __builtin_amdgcn_mfma_f32_16x16x32_bf16(af[ii], bfr[jj], acc[ii][jj], 0, 0, 0);
            p ^= 1;
        }
    }

    // epilogue: lane L, reg r -> row = lq*4 + r, col = lr (within 16x16 tile)
    float rs[4][4], rs2[4][4];
#pragma unroll
    for (int i = 0; i < 4; ++i)
#pragma unroll
        for (int r = 0; r < 4; ++r) { rs[i][r] = 0.f; rs2[i][r] = 0.f; }

#pragma unroll
    for (int i = 0; i < 4; ++i) {
#pragma unroll
        for (int r = 0; r < 4; ++r) {
            int row = m0 + wm + i * 16 + lq * 4 + r;
            float brow = (BIASMODE == 1) ? bias[row] : 0.f;
#pragma unroll
            for (int j = 0; j < 4; ++j) {
                int col = n0 + wn + j * 16 + lr;
                float v = acc[i][j][r] * scale;
                if (BIASMODE == 1) v += brow;
                if (BIASMODE == 2) v += bias[col];
                if (RELU) v = fmaxf(v, 0.f);
                size_t off = (size_t)b * strideC + (size_t)row * ldc + col;
                if (RESMODE == 1) v += ((const float*)resid)[off];
                if (RESMODE == 2) v += bf2f(((const unsigned short*)resid)[off]);
                if (BNSTAT) { rs[i][r] += v; rs2[i][r] += v * v; }
                if (OUTBF16) ((unsigned short*)C)[off] = f2bf(v);
                else         ((float*)C)[off] = v;
            }
        }
    }

    if (BNSTAT) {
#pragma unroll
        for (int i = 0; i < 4; ++i) {
#pragma unroll
            for (int r = 0; r < 4; ++r) {
                float a = rs[i][r], a2 = rs2[i][r];
#pragma unroll
                for (int off = 1; off < 16; off <<= 1) {
                    a  += __shfl_xor(a,  off, 64);
                    a2 += __shfl_xor(a2, off, 64);
                }
                if (lr == 0) {
                    int row = m0 + wm + i * 16 + lq * 4 + r;  // channel index
                    atomicAdd(&bnsum[row], a);
                    atomicAdd(&bnsum[512 + row], a2);
                }
            }
        }
    }
}

extern "C" void kernel_launch(void* const* d_in, const int* in_sizes, int n_in,
                              void* d_out, int out_size, void* d_ws, size_t ws_size,
                              hipStream_t stream) {
    const float* x     = (const float*)d_in[0];
    const float* bn1_g = (const float*)d_in[1];
    const float* bn1_b = (const float*)d_in[2];
    const float* W_qkv = (const float*)d_in[3];
    const float* b_qkv = (const float*)d_in[4];
    const float* bn2_g = (const float*)d_in[5];
    const float* bn2_b = (const float*)d_in[6];
    const float* W1    = (const float*)d_in[7];
    const float* b1    = (const float*)d_in[8];
    const float* W2    = (const float*)d_in[9];
    const float* b2    = (const float*)d_in[10];
    float* out = (float*)d_out;
    char* ws = (char*)d_ws;

    // workspace layout (bytes), ~170 MB total:
    unsigned short* hT    = (unsigned short*)(ws);                 // 32 MB (hT -> ybnT)
    unsigned short* qkT   = (unsigned short*)(ws + 33554432);      // 8 MB
    unsigned short* v     = (unsigned short*)(ws + 41943040);      // 32 MB (v -> y1T)
    unsigned short* betaT = (unsigned short*)(ws + 75497472);      // 64 MB
    unsigned short* xr    = (unsigned short*)(ws + 142606336);     // 32 MB (bf16 xr)
    unsigned short* Wqkvb = (unsigned short*)(ws + 176160768);     // 640 KB
    unsigned short* W1b   = (unsigned short*)(ws + 176816128);     // 512 KB
    unsigned short* W2b   = (unsigned short*)(ws + 177340416);     // 512 KB
    float* stats = (float*)(ws + 177864704);                       // mean1,rstd1,mean2,rstd2
    float* bnsum = (float*)(ws + 177873024);                       // 1024 f32 accumulators
    float* mean1 = stats,        *rstd1 = stats + 512;
    float* mean2 = stats + 1024, *rstd2 = stats + 1536;
    unsigned short* ybnT = hT;
    unsigned short* y1T  = v;

    const long sHT = (long)HWN * CC;    // 1024*512
    const long sQK = (long)HWN * 128;   // 1024*128
    const long sV  = (long)CC * HWN;    // 512*1024
    const long sBT = (long)HWN * HWN;   // 1024*1024

    // 0. weights -> bf16; zero bn2 accumulators
    cvt_bf16_kernel<<<(OO * CC + 255) / 256, 256, 0, stream>>>(W_qkv, Wqkvb, OO * CC);
    cvt_bf16_kernel<<<(CC * CC + 255) / 256, 256, 0, stream>>>(W1, W1b, CC * CC);
    cvt_bf16_kernel<<<(CC * CC + 255) / 256, 256, 0, stream>>>(W2, W2b, CC * CC);
    zero_kernel<<<4, 256, 0, stream>>>(bnsum, 1024);
    // 1. bn1 stats (fp32 x)
    bn_stats_kernel<<<CC, 256, 0, stream>>>(x, mean1, rstd1);
    // 2. hT[b][s][c] = relu(bn1(x)) transposed, bf16
    bn_apply_t_kernel<true, false><<<dim3(16, 8, BB), 256, 0, stream>>>(x, mean1, rstd1, bn1_g, bn1_b, hT);
    // 3a. qkT[s][o'] = hT @ Wqk^T + b_qkv[o']   (M=1024, N=128, K=512), col bias
    mfma_gemm<true, 2, false, 0, 0, false><<<dim3(1, 8, BB), 256, 0, stream>>>(
        hT, Wqkvb, b_qkv, nullptr, qkT, nullptr, 512, 512, 512, 128, sHT, 0, sQK, 1.f);
    // 3b. v[c][s] = Wv @ h + b_qkv[128+c]       (M=512, N=1024, K=512), row bias
    mfma_gemm<true, 1, false, 0, 0, false><<<dim3(8, 4, BB), 256, 0, stream>>>(
        Wqkvb + 128 * 512, hT, b_qkv + 128, nullptr, v, nullptr, 512, 512, 512, 1024, 0, sHT, sV, 1.f);
    // 4. betaT[kj][qi] = (kT @ qT^T)/8          (M=1024, N=1024, K=64)
    mfma_gemm<true, 0, false, 0, 0, false><<<dim3(8, 8, BB), 256, 0, stream>>>(
        qkT + 64, qkT, nullptr, nullptr, betaT, nullptr, 64, 128, 128, 1024, sQK, sQK, sBT, 0.125f);
    // 5. row softmax -> pT (in place)
    softmax_row_kernel<<<(BB * HWN) / 4, 256, 0, stream>>>(betaT);
    // 6. xr[c][s] = v @ pT^T + x, bf16 out      (M=512, N=1024, K=1024), fp32 resid,
    //    VGPR staging + fused bn2-stat accumulation
    mfma_gemm<true, 0, false, 1, 1, true><<<dim3(8, 4, BB), 256, 0, stream>>>(
        v, betaT, nullptr, x, xr, bnsum, 1024, 1024, 1024, 1024, sV, sBT, sV, 1.f);
    // 7. finalize bn2 stats
    finalize_bn2_kernel<<<2, 256, 0, stream>>>(bnsum, mean2, rstd2);
    // 8. ybnT[s][c] = bn2(xr) transposed, bf16 (aliases hT)
    bn_apply_t_kernel<false, true><<<dim3(16, 8, BB), 256, 0, stream>>>(xr, mean2, rstd2, bn2_g, bn2_b, ybnT);
    // 9. y1T[s][o] = relu(ybnT @ W1^T + b1)     (M=1024, N=512, K=512), col bias (aliases v)
    mfma_gemm<true, 2, true, 0, 0, false><<<dim3(4, 8, BB), 256, 0, stream>>>(
        ybnT, W1b, b1, nullptr, y1T, nullptr, 512, 512, 512, 512, sHT, 0, sHT, 1.f);
    // 10. out[c][s] = W2 @ y1T^T + b2 + xr(bf16) -> d_out fp32  (M=512, N=1024, K=512), VGPR staging
    mfma_gemm<false, 1, false, 2, 1, false><<<dim3(8, 4, BB), 256, 0, stream>>>(
        W2b, y1T, b2, xr, out, nullptr, 512, 512, 512, 1024, 0, sHT, sV, 1.f);
}